// Round 1
// baseline (449.968 us; speedup 1.0000x reference)
//
#include <hip/hip_runtime.h>
#include <math.h>

// Problem constants (B=4, L=8192, SEG=2048, RATE=4, D=768)
#define SEGLEN 2048
#define SRATE 4
#define DIM 768
#define BATCH 4
#define LFULL 8192
#define LSP 2048                 // sparsified length per batch (4 segs * 512)
#define NROWS (BATCH * LSP)      // 8192 total sparsified rows
#define LN_EPS 1e-5f
#define ATT_SCALE 0.03608439182435161f   // 1/sqrt(768)

typedef __attribute__((ext_vector_type(8))) short s16x8;
typedef __attribute__((ext_vector_type(4))) float f32x4;

__device__ __forceinline__ ushort f2bf(float f) {
    unsigned u = __float_as_uint(f);
    u += 0x7fffu + ((u >> 16) & 1u);      // RNE
    return (ushort)(u >> 16);
}
__device__ __forceinline__ float bf2f(ushort h) {
    return __uint_as_float(((unsigned)h) << 16);
}

// ---------------------------------------------------------------------------
// Gather sparsified rows (every RATE-th within each segment) + fp32->bf16.
// dst[r][d], r = b*2048 + seg*512 + j  <-  src[b*8192 + seg*2048 + j*4][d]
// ---------------------------------------------------------------------------
__global__ void pack_gather(const float* __restrict__ src, ushort* __restrict__ dst) {
    int idx = blockIdx.x * 256 + threadIdx.x;        // one per 4 elements
    // total = NROWS * (DIM/4) = 8192*192 = 1,572,864 (exact grid)
    int r  = idx / (DIM / 4);
    int dg = idx - r * (DIM / 4);
    int bb = r >> 11;            // /2048
    int s  = r & 2047;
    int seg = s >> 9;            // /512
    int j   = s & 511;
    long srow = (long)bb * LFULL + seg * SEGLEN + j * SRATE;
    float4 f = *(const float4*)(src + srow * DIM + dg * 4);
    ushort4 o;
    o.x = f2bf(f.x); o.y = f2bf(f.y); o.z = f2bf(f.z); o.w = f2bf(f.w);
    *(ushort4*)(dst + (long)r * DIM + dg * 4) = o;
}

// Plain fp32 -> bf16 conversion (weights). n4 = elements/4, exact grid.
__global__ void convert_bf(const float* __restrict__ src, ushort* __restrict__ dst) {
    int idx = blockIdx.x * 256 + threadIdx.x;
    float4 f = *(const float4*)(src + (long)idx * 4);
    ushort4 o;
    o.x = f2bf(f.x); o.y = f2bf(f.y); o.z = f2bf(f.z); o.w = f2bf(f.w);
    *(ushort4*)(dst + (long)idx * 4) = o;
}

// ---------------------------------------------------------------------------
// BT-GEMM: C[i][j] = sum_k A[i][k] * B[j][k]   (A: MxK, B: NxK, both bf16
// K-contiguous). 128x128 tile, BK=32, 256 threads = 4 waves (2x2), each wave
// 64x64 = 4x4 MFMA 16x16x32 tiles. fp32 accumulation.
// MODE 0: store bf16 C row-major (ldc)                       [proj q,k]
// MODE 1: store bf16 C transposed per batch: vT[b][col][row] [proj v]
// MODE 2: e=exp(acc*scale); store bf16 P row-major + atomicAdd row-sums [QK]
// MODE 3: store fp32 C row-major                              [PV]
// ---------------------------------------------------------------------------
#define GTILE 128
#define GBK 32
#define LDSP 40   // padded k-stride (ushorts): 80B rows, 16B aligned, 2-way-free banks

template<int MODE>
__global__ __launch_bounds__(256) void gemm_bt(
    const ushort* __restrict__ Ag, const ushort* __restrict__ Bg,
    ushort* __restrict__ Cb, float* __restrict__ Cf, float* __restrict__ lsum,
    int M, int N, int K, long sA, long sB, long sC, int ldc, float scale)
{
    __shared__ ushort As[GTILE * LDSP];
    __shared__ ushort Bs[GTILE * LDSP];

    const int z = blockIdx.z;
    const ushort* A = Ag + (long)z * sA;
    const ushort* B = Bg + (long)z * sB;

    const int tid = threadIdx.x;
    const int rowBase = blockIdx.y * GTILE;
    const int colBase = blockIdx.x * GTILE;
    const int wid = tid >> 6, lane = tid & 63;
    const int wm = wid >> 1, wn = wid & 1;
    const int quad = lane >> 4, lr = lane & 15;

    f32x4 acc[4][4] = {};

    const int idx0 = tid;          // staging: idx -> row = idx>>2, kgroup = idx&3
    const int idx1 = tid + 256;

    for (int k0 = 0; k0 < K; k0 += GBK) {
        uint4 a0 = *(const uint4*)(A + (long)(rowBase + (idx0 >> 2)) * K + k0 + (idx0 & 3) * 8);
        uint4 a1 = *(const uint4*)(A + (long)(rowBase + (idx1 >> 2)) * K + k0 + (idx1 & 3) * 8);
        uint4 b0 = *(const uint4*)(B + (long)(colBase + (idx0 >> 2)) * K + k0 + (idx0 & 3) * 8);
        uint4 b1 = *(const uint4*)(B + (long)(colBase + (idx1 >> 2)) * K + k0 + (idx1 & 3) * 8);
        __syncthreads();   // protect previous iteration's LDS reads
        *(uint4*)&As[(idx0 >> 2) * LDSP + (idx0 & 3) * 8] = a0;
        *(uint4*)&As[(idx1 >> 2) * LDSP + (idx1 & 3) * 8] = a1;
        *(uint4*)&Bs[(idx0 >> 2) * LDSP + (idx0 & 3) * 8] = b0;
        *(uint4*)&Bs[(idx1 >> 2) * LDSP + (idx1 & 3) * 8] = b1;
        __syncthreads();

        s16x8 af[4], bfm[4];
#pragma unroll
        for (int t = 0; t < 4; t++)
            af[t] = *(const s16x8*)&As[(wm * 64 + t * 16 + lr) * LDSP + quad * 8];
#pragma unroll
        for (int t = 0; t < 4; t++)
            bfm[t] = *(const s16x8*)&Bs[(wn * 64 + t * 16 + lr) * LDSP + quad * 8];
#pragma unroll
        for (int i = 0; i < 4; i++)
#pragma unroll
            for (int j = 0; j < 4; j++)
                acc[i][j] = __builtin_amdgcn_mfma_f32_16x16x32_bf16(af[i], bfm[j], acc[i][j], 0, 0, 0);
    }

    // Epilogue. D mapping: col = lane&15 (b-operand row), row = quad*4+reg.
    if (MODE == 0) {
        ushort* Cz = Cb + (long)z * sC;
#pragma unroll
        for (int i = 0; i < 4; i++) {
            int r0 = rowBase + wm * 64 + i * 16 + quad * 4;
#pragma unroll
            for (int j = 0; j < 4; j++) {
                int c = colBase + wn * 64 + j * 16 + lr;
#pragma unroll
                for (int reg = 0; reg < 4; reg++)
                    Cz[(long)(r0 + reg) * ldc + c] = f2bf(acc[i][j][reg]);
            }
        }
    } else if (MODE == 1) {
        // vT[b][c][j], b = row>>11, j = row&2047 (rows of a tile stay in-batch)
#pragma unroll
        for (int i = 0; i < 4; i++) {
            int r0 = rowBase + wm * 64 + i * 16 + quad * 4;
            int bidx = r0 >> 11;
            int jj = r0 & 2047;
            ushort* Cz = Cb + (long)bidx * DIM * LSP;
#pragma unroll
            for (int j = 0; j < 4; j++) {
                int c = colBase + wn * 64 + j * 16 + lr;
                ushort4 o;
                o.x = f2bf(acc[i][j][0]); o.y = f2bf(acc[i][j][1]);
                o.z = f2bf(acc[i][j][2]); o.w = f2bf(acc[i][j][3]);
                *(ushort4*)(Cz + (long)c * LSP + jj) = o;
            }
        }
    } else if (MODE == 2) {
        ushort* Cz = Cb + (long)z * sC;
        float* lz = lsum + (long)z * M;
#pragma unroll
        for (int i = 0; i < 4; i++) {
            int r0 = rowBase + wm * 64 + i * 16 + quad * 4;
#pragma unroll
            for (int reg = 0; reg < 4; reg++) {
                float s = 0.f;
#pragma unroll
                for (int j = 0; j < 4; j++) {
                    int c = colBase + wn * 64 + j * 16 + lr;
                    float e = expf(acc[i][j][reg] * scale);   // no max needed: |logit| <= sqrt(768)
                    s += e;
                    Cz[(long)(r0 + reg) * ldc + c] = f2bf(e);
                }
                for (int m = 1; m < 16; m <<= 1) s += __shfl_xor(s, m, 64);
                if (lr == 0) atomicAdd(&lz[r0 + reg], s);
            }
        }
    } else { // MODE 3
        float* Cz = Cf + (long)z * sC;
#pragma unroll
        for (int i = 0; i < 4; i++) {
            int r0 = rowBase + wm * 64 + i * 16 + quad * 4;
#pragma unroll
            for (int j = 0; j < 4; j++) {
                int c = colBase + wn * 64 + j * 16 + lr;
#pragma unroll
                for (int reg = 0; reg < 4; reg++)
                    Cz[(long)(r0 + reg) * ldc + c] = acc[i][j][reg];
            }
        }
    }
}

// ---------------------------------------------------------------------------
// In-place LayerNorm over DIM=768 bf16 values. One wave per row (12 elem/lane).
// ---------------------------------------------------------------------------
__global__ __launch_bounds__(256) void ln_inplace(
    ushort* __restrict__ X, const float* __restrict__ gamma,
    const float* __restrict__ beta)
{
    int wid = threadIdx.x >> 6, lane = threadIdx.x & 63;
    int row = blockIdx.x * 4 + wid;
    ushort* xp = X + (long)row * DIM;
    float v[12];
    float s = 0.f;
#pragma unroll
    for (int c = 0; c < 12; c++) { v[c] = bf2f(xp[c * 64 + lane]); s += v[c]; }
    for (int m = 1; m < 64; m <<= 1) s += __shfl_xor(s, m, 64);
    float mean = s * (1.0f / 768.0f);
    float q = 0.f;
#pragma unroll
    for (int c = 0; c < 12; c++) { float d = v[c] - mean; q += d * d; }
    for (int m = 1; m < 64; m <<= 1) q += __shfl_xor(q, m, 64);
    float rstd = rsqrtf(q * (1.0f / 768.0f) + LN_EPS);
#pragma unroll
    for (int c = 0; c < 12; c++) {
        int idx = c * 64 + lane;
        float y = (v[c] - mean) * rstd * gamma[idx] + beta[idx];
        xp[idx] = f2bf(y);
    }
}

// ---------------------------------------------------------------------------
// out[row] = softmax_over_d( O[row]/l[row] ). One wave per row.
// ---------------------------------------------------------------------------
__global__ __launch_bounds__(256) void final_softmax(
    const float* __restrict__ O, const float* __restrict__ l, float* __restrict__ out)
{
    int wid = threadIdx.x >> 6, lane = threadIdx.x & 63;
    int row = blockIdx.x * 4 + wid;
    const float* op = O + (long)row * DIM;
    float inv = 1.0f / l[row];
    float v[12]; float mx = -1e30f;
#pragma unroll
    for (int c = 0; c < 12; c++) { v[c] = op[c * 64 + lane] * inv; mx = fmaxf(mx, v[c]); }
    for (int m = 1; m < 64; m <<= 1) mx = fmaxf(mx, __shfl_xor(mx, m, 64));
    float s = 0.f;
#pragma unroll
    for (int c = 0; c < 12; c++) { v[c] = expf(v[c] - mx); s += v[c]; }
    for (int m = 1; m < 64; m <<= 1) s += __shfl_xor(s, m, 64);
    float invs = 1.0f / s;
#pragma unroll
    for (int c = 0; c < 12; c++) out[(long)row * DIM + c * 64 + lane] = v[c] * invs;
}

// ---------------------------------------------------------------------------
extern "C" void kernel_launch(void* const* d_in, const int* in_sizes, int n_in,
                              void* d_out, int out_size, void* d_ws, size_t ws_size,
                              hipStream_t stream)
{
    const float* Q  = (const float*)d_in[0];
    const float* K_ = (const float*)d_in[1];
    const float* V  = (const float*)d_in[2];
    const float* Wq = (const float*)d_in[3];
    const float* Wk = (const float*)d_in[4];
    const float* Wv = (const float*)d_in[5];
    const float* g  = (const float*)d_in[6];
    const float* b  = (const float*)d_in[7];
    float* out = (float*)d_out;

    char* ws = (char*)d_ws;
    // Workspace layout (bytes). Total ~104.3 MB. P aliases the consumed X region.
    ushort* Xq  = (ushort*)(ws + 0);            // 12,582,912 each
    ushort* Xk  = (ushort*)(ws + 12582912);
    ushort* Xv  = (ushort*)(ws + 25165824);
    ushort* Wqb = (ushort*)(ws + 37748736);     // 1,179,648 each
    ushort* Wkb = (ushort*)(ws + 38928384);
    ushort* Wvb = (ushort*)(ws + 40108032);
    ushort* qb  = (ushort*)(ws + 41287680);     // 12,582,912 each (qb,kb contiguous)
    ushort* kb  = (ushort*)(ws + 53870592);
    ushort* vT  = (ushort*)(ws + 66453504);     // 12,582,912
    float*  O   = (float*)(ws + 79036416);      // 25,165,824
    float*  l   = (float*)(ws + 104202240);     // 32,768
    ushort* P   = (ushort*)(ws + 0);            // 33,554,432 (alias X, lifetime-disjoint)

    (void)in_sizes; (void)n_in; (void)out_size; (void)ws_size;

    hipMemsetAsync(l, 0, NROWS * sizeof(float), stream);

    // 1) gather sparsified rows -> bf16
    pack_gather<<<6144, 256, 0, stream>>>(Q,  Xq);
    pack_gather<<<6144, 256, 0, stream>>>(K_, Xk);
    pack_gather<<<6144, 256, 0, stream>>>(V,  Xv);
    // 2) weights -> bf16 (768*768/4/256 = 576 blocks each)
    convert_bf<<<576, 256, 0, stream>>>(Wq, Wqb);
    convert_bf<<<576, 256, 0, stream>>>(Wk, Wkb);
    convert_bf<<<576, 256, 0, stream>>>(Wv, Wvb);

    // 3) projections: q,k batched (z=2), v with transpose epilogue
    {
        dim3 grid(DIM / GTILE, NROWS / GTILE, 2);   // (6,64,2)
        gemm_bt<0><<<grid, 256, 0, stream>>>(Xq, Wqb, qb, nullptr, nullptr,
            NROWS, DIM, DIM, (long)NROWS * DIM, (long)DIM * DIM, (long)NROWS * DIM, DIM, 0.f);
    }
    {
        dim3 grid(DIM / GTILE, NROWS / GTILE, 1);   // (6,64)
        gemm_bt<1><<<grid, 256, 0, stream>>>(Xv, Wvb, vT, nullptr, nullptr,
            NROWS, DIM, DIM, 0, 0, 0, DIM, 0.f);
    }
    // 4) LayerNorm q and k in place (qb,kb contiguous: 16384 rows)
    ln_inplace<<<4096, 256, 0, stream>>>(qb, g, b);

    // 5) P = exp(scale * q k^T), row-sums into l
    {
        dim3 grid(LSP / GTILE, LSP / GTILE, BATCH); // (16,16,4)
        gemm_bt<2><<<grid, 256, 0, stream>>>(qb, kb, P, nullptr, l,
            LSP, LSP, DIM, (long)LSP * DIM, (long)LSP * DIM, (long)LSP * LSP, LSP, ATT_SCALE);
    }
    // 6) O = P @ v   (B operand = vT, K=2048)
    {
        dim3 grid(DIM / GTILE, LSP / GTILE, BATCH); // (6,16,4)
        gemm_bt<3><<<grid, 256, 0, stream>>>(P, vT, nullptr, O, nullptr,
            LSP, DIM, LSP, (long)LSP * LSP, (long)DIM * LSP, (long)LSP * DIM, DIM, 0.f);
    }
    // 7) out = softmax_d(O / l)
    final_softmax<<<2048, 256, 0, stream>>>(O, l, out);
}

// Round 2
// 424.577 us; speedup vs baseline: 1.0598x; 1.0598x over previous
//
#include <hip/hip_runtime.h>
#include <math.h>

// Problem constants (B=4, L=8192, SEG=2048, RATE=4, D=768)
#define SEGLEN 2048
#define SRATE 4
#define DIM 768
#define BATCH 4
#define LFULL 8192
#define LSP 2048                 // sparsified length per batch (4 segs * 512)
#define NROWS (BATCH * LSP)      // 8192 total sparsified rows
#define LN_EPS 1e-5f
#define ATT_SCALE 0.03608439182435161f   // 1/sqrt(768)

typedef __attribute__((ext_vector_type(8))) short s16x8;
typedef __attribute__((ext_vector_type(4))) float f32x4;

__device__ __forceinline__ ushort f2bf(float f) {
    unsigned u = __float_as_uint(f);
    u += 0x7fffu + ((u >> 16) & 1u);      // RNE
    return (ushort)(u >> 16);
}
__device__ __forceinline__ float bf2f(ushort h) {
    return __uint_as_float(((unsigned)h) << 16);
}

// async global->LDS, 16B per lane. LDS dest is wave-uniform base + lane*16.
__device__ __forceinline__ void ld_lds16(const ushort* g, ushort* l) {
    __builtin_amdgcn_global_load_lds(
        (const __attribute__((address_space(1))) void*)g,
        (__attribute__((address_space(3))) void*)l, 16, 0, 0);
}

// ---------------------------------------------------------------------------
// Gather sparsified rows (every RATE-th within each segment) + fp32->bf16.
// z selects Q/K/V. dst r = b*2048 + seg*512 + j <- src[b*8192 + seg*2048 + j*4]
// ---------------------------------------------------------------------------
__global__ void pack3(const float* __restrict__ Q, const float* __restrict__ Ks,
                      const float* __restrict__ V, ushort* __restrict__ X) {
    const float* src = blockIdx.z == 0 ? Q : blockIdx.z == 1 ? Ks : V;
    ushort* dst = X + (long)blockIdx.z * (NROWS * DIM);
    int idx = blockIdx.x * 256 + threadIdx.x;        // one per 4 elements
    int r  = idx / (DIM / 4);
    int dg = idx - r * (DIM / 4);
    int bb = r >> 11;            // /2048
    int s  = r & 2047;
    int seg = s >> 9;            // /512
    int j   = s & 511;
    long srow = (long)bb * LFULL + seg * SEGLEN + j * SRATE;
    float4 f = *(const float4*)(src + srow * DIM + dg * 4);
    ushort4 o;
    o.x = f2bf(f.x); o.y = f2bf(f.y); o.z = f2bf(f.z); o.w = f2bf(f.w);
    *(ushort4*)(dst + (long)r * DIM + dg * 4) = o;
}

// weights fp32 -> bf16, z selects Wq/Wk/Wv; dst contiguous
__global__ void conv3(const float* __restrict__ Wq, const float* __restrict__ Wk,
                      const float* __restrict__ Wv, ushort* __restrict__ W) {
    const float* src = blockIdx.z == 0 ? Wq : blockIdx.z == 1 ? Wk : Wv;
    ushort* dst = W + (long)blockIdx.z * (DIM * DIM);
    int idx = blockIdx.x * 256 + threadIdx.x;
    float4 f = *(const float4*)(src + (long)idx * 4);
    ushort4 o;
    o.x = f2bf(f.x); o.y = f2bf(f.y); o.z = f2bf(f.z); o.w = f2bf(f.w);
    *(ushort4*)(dst + (long)idx * 4) = o;
}

// ---------------------------------------------------------------------------
// BT-GEMM: C[i][j] = sum_k A[i][k] * B[j][k]  (both operands K-contiguous bf16)
// 128x128 tile, BK=32, 256 thr = 4 waves (2x2), each wave 64x64 (4x4 MFMA).
// m97 structure: global_load_lds dwordx4 staging into unpadded LDS (64B rows).
// MODE 0: z<2 -> bf16 row-major to Cb+z*sC; z==2 -> transposed vT to Cb2 [proj]
// MODE 2: e=__expf(acc*scale); bf16 P row-major + atomicAdd row-sums     [QK]
// MODE 3: split-K: z=(batch,half); fp32 row-major to (half? Cf2 : Cf)   [PV]
// ---------------------------------------------------------------------------
#define GTILE 128
#define GBK 32

template<int MODE>
__global__ __launch_bounds__(256) void gemm_bt(
    const ushort* __restrict__ Ag, const ushort* __restrict__ Bg,
    ushort* __restrict__ Cb, ushort* __restrict__ Cb2,
    float* __restrict__ Cf, float* __restrict__ Cf2, float* __restrict__ lsum,
    int M, int N, int K, int lda, int ldb, long sA, long sB, long sC,
    int ldc, float scale)
{
    __shared__ ushort As[GTILE * GBK];   // 8 KB, unpadded: row stride 32 ushorts
    __shared__ ushort Bs[GTILE * GBK];

    const int z = blockIdx.z;
    const int bz = (MODE == 3) ? (z >> 1) : z;
    const int hz = (MODE == 3) ? (z & 1) : 0;
    const ushort* A = Ag + (long)bz * sA + (long)hz * K;
    const ushort* B = Bg + (long)bz * sB + (long)hz * K;

    const int tid = threadIdx.x;
    const int rowBase = blockIdx.y * GTILE;
    const int colBase = blockIdx.x * GTILE;
    const int wid = tid >> 6, lane = tid & 63;
    const int wm = wid >> 1, wn = wid & 1;
    const int quad = lane >> 4, lr = lane & 15;

    f32x4 acc[4][4] = {};

    // staging: wave wid owns slabs {2*wid, 2*wid+1} of both A and B.
    // slab = 16 rows x 64B; lane i -> row slab*16 + i/4, kgroup i%4.
    const ushort* gA = A + (long)(rowBase + wid * 32 + (lane >> 2)) * lda + (lane & 3) * 8;
    const ushort* gB = B + (long)(colBase + wid * 32 + (lane >> 2)) * ldb + (lane & 3) * 8;
    ushort* lA = As + wid * 1024;   // wave-uniform
    ushort* lB = Bs + wid * 1024;

    for (int k0 = 0; k0 < K; k0 += GBK) {
        __syncthreads();                       // prev iter's ds_reads done
        ld_lds16(gA + k0, lA);
        ld_lds16(gA + 16 * lda + k0, lA + 512);
        ld_lds16(gB + k0, lB);
        ld_lds16(gB + 16 * ldb + k0, lB + 512);
        __syncthreads();                       // compiler drains vmcnt before barrier

        s16x8 af[4], bfm[4];
#pragma unroll
        for (int t = 0; t < 4; t++)
            af[t] = *(const s16x8*)&As[(wm * 64 + t * 16 + lr) * GBK + quad * 8];
#pragma unroll
        for (int t = 0; t < 4; t++)
            bfm[t] = *(const s16x8*)&Bs[(wn * 64 + t * 16 + lr) * GBK + quad * 8];
#pragma unroll
        for (int i = 0; i < 4; i++)
#pragma unroll
            for (int j = 0; j < 4; j++)
                acc[i][j] = __builtin_amdgcn_mfma_f32_16x16x32_bf16(af[i], bfm[j], acc[i][j], 0, 0, 0);
    }

    // Epilogue. D mapping: col = lane&15 (B-operand row), row = quad*4+reg.
    if (MODE == 0) {
        if (z < 2) {
            ushort* Cz = Cb + (long)z * sC;
#pragma unroll
            for (int i = 0; i < 4; i++) {
                int r0 = rowBase + wm * 64 + i * 16 + quad * 4;
#pragma unroll
                for (int j = 0; j < 4; j++) {
                    int c = colBase + wn * 64 + j * 16 + lr;
#pragma unroll
                    for (int reg = 0; reg < 4; reg++)
                        Cz[(long)(r0 + reg) * ldc + c] = f2bf(acc[i][j][reg]);
                }
            }
        } else {
            // v-projection: store transposed vT[b][col][row]
#pragma unroll
            for (int i = 0; i < 4; i++) {
                int r0 = rowBase + wm * 64 + i * 16 + quad * 4;
                int bidx = r0 >> 11;
                int jj = r0 & 2047;
                ushort* Cz = Cb2 + (long)bidx * DIM * LSP;
#pragma unroll
                for (int j = 0; j < 4; j++) {
                    int c = colBase + wn * 64 + j * 16 + lr;
                    ushort4 o;
                    o.x = f2bf(acc[i][j][0]); o.y = f2bf(acc[i][j][1]);
                    o.z = f2bf(acc[i][j][2]); o.w = f2bf(acc[i][j][3]);
                    *(ushort4*)(Cz + (long)c * LSP + jj) = o;
                }
            }
        }
    } else if (MODE == 2) {
        ushort* Cz = Cb + (long)z * sC;
        float* lz = lsum + (long)z * M;
#pragma unroll
        for (int i = 0; i < 4; i++) {
            int r0 = rowBase + wm * 64 + i * 16 + quad * 4;
#pragma unroll
            for (int reg = 0; reg < 4; reg++) {
                float s = 0.f;
#pragma unroll
                for (int j = 0; j < 4; j++) {
                    int c = colBase + wn * 64 + j * 16 + lr;
                    float e = __expf(acc[i][j][reg] * scale);  // |logit|<=sqrt(768): no max needed
                    s += e;
                    Cz[(long)(r0 + reg) * ldc + c] = f2bf(e);
                }
                for (int m = 1; m < 16; m <<= 1) s += __shfl_xor(s, m, 64);
                if (lr == 0) atomicAdd(&lz[r0 + reg], s);
            }
        }
    } else { // MODE 3 split-K
        float* Cz = (hz ? Cf2 : Cf) + (long)bz * sC;
#pragma unroll
        for (int i = 0; i < 4; i++) {
            int r0 = rowBase + wm * 64 + i * 16 + quad * 4;
#pragma unroll
            for (int j = 0; j < 4; j++) {
                int c = colBase + wn * 64 + j * 16 + lr;
#pragma unroll
                for (int reg = 0; reg < 4; reg++)
                    Cz[(long)(r0 + reg) * ldc + c] = acc[i][j][reg];
            }
        }
    }
}

// ---------------------------------------------------------------------------
// In-place LayerNorm over DIM=768 bf16 values. One wave per row (12 elem/lane).
// ---------------------------------------------------------------------------
__global__ __launch_bounds__(256) void ln_inplace(
    ushort* __restrict__ X, const float* __restrict__ gamma,
    const float* __restrict__ beta)
{
    int wid = threadIdx.x >> 6, lane = threadIdx.x & 63;
    int row = blockIdx.x * 4 + wid;
    ushort* xp = X + (long)row * DIM;
    float v[12];
    float s = 0.f;
#pragma unroll
    for (int c = 0; c < 12; c++) { v[c] = bf2f(xp[c * 64 + lane]); s += v[c]; }
    for (int m = 1; m < 64; m <<= 1) s += __shfl_xor(s, m, 64);
    float mean = s * (1.0f / 768.0f);
    float q = 0.f;
#pragma unroll
    for (int c = 0; c < 12; c++) { float d = v[c] - mean; q += d * d; }
    for (int m = 1; m < 64; m <<= 1) q += __shfl_xor(q, m, 64);
    float rstd = rsqrtf(q * (1.0f / 768.0f) + LN_EPS);
#pragma unroll
    for (int c = 0; c < 12; c++) {
        int idx = c * 64 + lane;
        float y = (v[c] - mean) * rstd * gamma[idx] + beta[idx];
        xp[idx] = f2bf(y);
    }
}

// ---------------------------------------------------------------------------
// out[row] = softmax_over_d( (O0[row]+O1[row]) / l[row] ). One wave per row.
// ---------------------------------------------------------------------------
__global__ __launch_bounds__(256) void final_softmax(
    const float* __restrict__ O0, const float* __restrict__ O1,
    const float* __restrict__ l, float* __restrict__ out)
{
    int wid = threadIdx.x >> 6, lane = threadIdx.x & 63;
    int row = blockIdx.x * 4 + wid;
    long base = (long)row * DIM;
    float inv = 1.0f / l[row];
    float v[12]; float mx = -1e30f;
#pragma unroll
    for (int c = 0; c < 12; c++) {
        v[c] = (O0[base + c * 64 + lane] + O1[base + c * 64 + lane]) * inv;
        mx = fmaxf(mx, v[c]);
    }
    for (int m = 1; m < 64; m <<= 1) mx = fmaxf(mx, __shfl_xor(mx, m, 64));
    float s = 0.f;
#pragma unroll
    for (int c = 0; c < 12; c++) { v[c] = __expf(v[c] - mx); s += v[c]; }
    for (int m = 1; m < 64; m <<= 1) s += __shfl_xor(s, m, 64);
    float invs = 1.0f / s;
#pragma unroll
    for (int c = 0; c < 12; c++) out[base + c * 64 + lane] = v[c] * invs;
}

// ---------------------------------------------------------------------------
extern "C" void kernel_launch(void* const* d_in, const int* in_sizes, int n_in,
                              void* d_out, int out_size, void* d_ws, size_t ws_size,
                              hipStream_t stream)
{
    const float* Q  = (const float*)d_in[0];
    const float* K_ = (const float*)d_in[1];
    const float* V  = (const float*)d_in[2];
    const float* Wq = (const float*)d_in[3];
    const float* Wk = (const float*)d_in[4];
    const float* Wv = (const float*)d_in[5];
    const float* g  = (const float*)d_in[6];
    const float* b  = (const float*)d_in[7];
    float* out = (float*)d_out;

    char* ws = (char*)d_ws;
    // Workspace layout (bytes). Total ~104.3 MB.
    // P aliases X (lifetime-disjoint); O1 aliases qb+kb (dead after QK).
    ushort* Xq  = (ushort*)(ws + 0);            // 12,582,912 each (Xq,Xk,Xv contig)
    ushort* Wqb = (ushort*)(ws + 37748736);     // 1,179,648 each (contig)
    ushort* qb  = (ushort*)(ws + 41287680);     // 12,582,912 each (qb,kb contig)
    ushort* kb  = (ushort*)(ws + 53870592);
    ushort* vT  = (ushort*)(ws + 66453504);     // 12,582,912
    float*  O0  = (float*)(ws + 79036416);      // 25,165,824
    float*  l   = (float*)(ws + 104202240);     // 32,768
    ushort* P   = (ushort*)(ws + 0);            // 33,554,432 (alias X)
    float*  O1  = (float*)(ws + 41287680);      // 25,165,824 (alias qb+kb)

    (void)in_sizes; (void)n_in; (void)out_size; (void)ws_size;

    hipMemsetAsync(l, 0, NROWS * sizeof(float), stream);

    // 1) gather sparsified rows -> bf16 (z = Q/K/V)
    pack3<<<dim3(6144, 1, 3), 256, 0, stream>>>(Q, K_, V, Xq);
    // 2) weights -> bf16 (z = Wq/Wk/Wv)
    conv3<<<dim3(576, 1, 3), 256, 0, stream>>>(Wq, Wk, Wv, Wqb);

    // 3) projections: z in {q,k,v}; v stores transposed (vT)
    gemm_bt<0><<<dim3(DIM / GTILE, NROWS / GTILE, 3), 256, 0, stream>>>(
        Xq, Wqb, qb, vT, nullptr, nullptr, nullptr,
        NROWS, DIM, DIM, DIM, DIM,
        (long)NROWS * DIM, (long)DIM * DIM, (long)NROWS * DIM, DIM, 0.f);

    // 4) LayerNorm q and k in place (qb,kb contiguous: 16384 rows)
    ln_inplace<<<4096, 256, 0, stream>>>(qb, g, b);

    // 5) P = exp(scale * q k^T), row-sums into l
    gemm_bt<2><<<dim3(LSP / GTILE, LSP / GTILE, BATCH), 256, 0, stream>>>(
        qb, kb, P, nullptr, nullptr, nullptr, l,
        LSP, LSP, DIM, DIM, DIM,
        (long)LSP * DIM, (long)LSP * DIM, (long)LSP * LSP, LSP, ATT_SCALE);

    // 6) O = P @ v, split-K x2 (z = batch*2 + half), B operand = vT
    gemm_bt<3><<<dim3(DIM / GTILE, LSP / GTILE, BATCH * 2), 256, 0, stream>>>(
        P, vT, nullptr, nullptr, O0, O1, nullptr,
        LSP, DIM, LSP / 2, LSP, LSP,
        (long)LSP * LSP, (long)DIM * LSP, (long)LSP * DIM, DIM, 0.f);

    // 7) out = softmax_d((O0+O1) / l)
    final_softmax<<<2048, 256, 0, stream>>>(O0, O1, l, out);
}